// Round 1
// baseline (1371.574 us; speedup 1.0000x reference)
//
#include <hip/hip_runtime.h>
#include <math.h>

// Problem constants (from reference)
#define P_N    (1 << 20)   // points
#define NTC    133         // NT = N_VARS + AUX + 1
#define KD     18          // K = ceil(sqrt(2*NT))+1
#define MD     16          // M
#define NV     68          // N_VARS
#define NSWEEP 40
#define NBLK_MAX 512

// JAX default since ~0.4.36/0.5: threefry_partitionable = True.
// If absmax fails, flip to 0 (legacy split-halves counter scheme).
#define THREEFRY_PARTITIONABLE 1

__device__ __forceinline__ void threefry2x32(unsigned k0, unsigned k1,
                                             unsigned x0, unsigned x1,
                                             unsigned& o0, unsigned& o1) {
  unsigned ks2 = k0 ^ k1 ^ 0x1BD11BDAu;
#define TFR(r) { x0 += x1; x1 = (x1 << (r)) | (x1 >> (32 - (r))); x1 ^= x0; }
  x0 += k0; x1 += k1;
  TFR(13) TFR(15) TFR(26) TFR(6)
  x0 += k1;  x1 += ks2 + 1u;
  TFR(17) TFR(29) TFR(16) TFR(24)
  x0 += ks2; x1 += k0 + 2u;
  TFR(13) TFR(15) TFR(26) TFR(6)
  x0 += k0;  x1 += k1 + 3u;
  TFR(17) TFR(29) TFR(16) TFR(24)
  x0 += k1;  x1 += ks2 + 4u;
  TFR(13) TFR(15) TFR(26) TFR(6)
  x0 += ks2; x1 += k0 + 5u;
#undef TFR
  o0 = x0; o1 = x1;
}

// bits -> uniform in [lo, 1) exactly as jax._src.random._uniform, then
// normal = sqrt(2)*erfinv(u). Giles' erfinvf + 2 Newton steps (double erf).
__device__ __forceinline__ float bits_to_normal(unsigned b) {
  float f = __uint_as_float((b >> 9) | 0x3f800000u);  // [1,2)
  const float lo = -0.99999994f, hi = 1.0f;
  float d = hi - lo;
  float u = fmaf(f, d, lo - d);  // (f-1)*d + lo
  u = fmaxf(lo, u);
  float w = -logf((1.0f - u) * (1.0f + u));
  float p;
  if (w < 5.0f) {
    w -= 2.5f;
    p = 2.81022636e-08f;
    p = fmaf(p, w, 3.43273939e-07f);
    p = fmaf(p, w, -3.5233877e-06f);
    p = fmaf(p, w, -4.39150654e-06f);
    p = fmaf(p, w, 0.00021858087f);
    p = fmaf(p, w, -0.00125372503f);
    p = fmaf(p, w, -0.00417768164f);
    p = fmaf(p, w, 0.246640727f);
    p = fmaf(p, w, 1.50140941f);
  } else {
    w = sqrtf(w) - 3.0f;
    p = -0.000200214257f;
    p = fmaf(p, w, 0.000100950558f);
    p = fmaf(p, w, 0.00134934322f);
    p = fmaf(p, w, -0.00367342844f);
    p = fmaf(p, w, 0.00573950773f);
    p = fmaf(p, w, -0.0076224613f);
    p = fmaf(p, w, 0.00943887047f);
    p = fmaf(p, w, 1.00167406f);
    p = fmaf(p, w, 2.83297682f);
  }
  double y = (double)(p * u);
  const double Kc = 0.8862269254527580136490837416706;  // sqrt(pi)/2
  double ud = (double)u;
  y = y - (erf(y) - ud) * Kc * exp(y * y);
  y = y - (erf(y) - ud) * Kc * exp(y * y);
  return 1.41421356237309504880f * (float)y;  // f32 sqrt(2) * erfinv
}

// ---------------- Kernel 1: streaming MLP reduction -------------------------
// acc[e], e = hidden*4 + action; deterministic per-block partials to ws.
__global__ __launch_bounds__(256) void k1_reduce(
    const float* __restrict__ points, const float* __restrict__ features,
    const float* __restrict__ W1, const float* __restrict__ b1,
    float* __restrict__ partials) {
  __shared__ float red[4][64];
  float w0[16], w1[16], bb[16];
#pragma unroll
  for (int k = 0; k < 16; ++k) {
    w0[k] = W1[2 * k]; w1[k] = W1[2 * k + 1]; bb[k] = b1[k];
  }
  float acc[64];
#pragma unroll
  for (int e = 0; e < 64; ++e) acc[e] = 0.f;
  const float2* p2 = (const float2*)points;
  const float4* f4 = (const float4*)features;
  int gid = blockIdx.x * blockDim.x + threadIdx.x;
  int stride = gridDim.x * blockDim.x;
  for (int p = gid; p < P_N; p += stride) {
    float2 pt = p2[p];
    float4 ft = f4[p];
#pragma unroll
    for (int k = 0; k < 16; ++k) {
      float x = fmaf(pt.x, w0[k], fmaf(pt.y, w1[k], bb[k]));
      float h = 1.0f / (1.0f + __expf(-x));
      acc[4 * k + 0] = fmaf(h, ft.x, acc[4 * k + 0]);
      acc[4 * k + 1] = fmaf(h, ft.y, acc[4 * k + 1]);
      acc[4 * k + 2] = fmaf(h, ft.z, acc[4 * k + 2]);
      acc[4 * k + 3] = fmaf(h, ft.w, acc[4 * k + 3]);
    }
  }
#pragma unroll
  for (int e = 0; e < 64; ++e) {
    float v = acc[e];
    v += __shfl_down(v, 32);
    v += __shfl_down(v, 16);
    v += __shfl_down(v, 8);
    v += __shfl_down(v, 4);
    v += __shfl_down(v, 2);
    v += __shfl_down(v, 1);
    acc[e] = v;
  }
  int lane = threadIdx.x & 63, wv = threadIdx.x >> 6;
  if (lane == 0) {
#pragma unroll
    for (int e = 0; e < 64; ++e) red[wv][e] = acc[e];
  }
  __syncthreads();
  if (threadIdx.x < 64)
    partials[blockIdx.x * 64 + threadIdx.x] =
        red[0][threadIdx.x] + red[1][threadIdx.x] +
        red[2][threadIdx.x] + red[3][threadIdx.x];
}

// ---------------- Kernel 2: finalize + SATNet mixing ------------------------
__global__ __launch_bounds__(256) void k2_satnet(
    const float* __restrict__ S, const int* __restrict__ is_input,
    const float* __restrict__ partials, int nblk, float* __restrict__ out) {
  __shared__ float Vm[KD][NTC];
  __shared__ __align__(16) float Sm[NTC][MD];
  __shared__ float Cd[NTC];
  __shared__ float zfv[NTC];
  __shared__ int fx[NTC];
  __shared__ float v0[KD];
  __shared__ float Ul[KD][MD];
  __shared__ float red2[4][64];

  int t = threadIdx.x;

  // --- reduce per-block partials ---
  {
    int g = t >> 6, e = t & 63;
    float s = 0.f;
    for (int b = g; b < nblk; b += 4) s += partials[b * 64 + e];
    red2[g][e] = s;
  }
  // --- load S ---
  for (int idx = t; idx < NTC * MD; idx += 256) ((float*)Sm)[idx] = S[idx];

  // --- V init: threefry normals ---
#if THREEFRY_PARTITIONABLE
  for (int e = t; e < KD * NTC; e += 256) {
    unsigned o0, o1;
    threefry2x32(0u, 42u, 0u, (unsigned)e, o0, o1);
    ((float*)Vm)[e] = bits_to_normal(o0 ^ o1);
  }
#else
  for (int pr = t; pr < (KD * NTC) / 2; pr += 256) {
    unsigned o0, o1;
    threefry2x32(0u, 42u, (unsigned)pr, (unsigned)(1197 + pr), o0, o1);
    ((float*)Vm)[pr] = bits_to_normal(o0);
    ((float*)Vm)[1197 + pr] = bits_to_normal(o1);
  }
#endif
  __syncthreads();

  // --- zf, fixed mask, Cd ---
  if (t < NTC) {
    float zv = 0.f;
    if (t == 0) zv = 1.f;
    else if (t <= 64) {
      float x = red2[0][t - 1] + red2[1][t - 1] + red2[2][t - 1] + red2[3][t - 1];
      zv = 1.0f / (1.0f + expf(-x));
    }
    zfv[t] = zv;
    int f = 0;
    if (t == 0) f = 1;
    else if (t <= NV) f = (is_input[t - 1] != 0) ? 1 : 0;
    fx[t] = f;
    float cd = 0.f;
#pragma unroll
    for (int m = 0; m < MD; ++m) cd += Sm[t][m] * Sm[t][m];
    Cd[t] = cd;
  }
  __syncthreads();

  // --- column-normalize V ---
  if (t < NTC) {
    float s = 0.f;
#pragma unroll
    for (int k = 0; k < KD; ++k) s += Vm[k][t] * Vm[k][t];
    float n = sqrtf(s);
#pragma unroll
    for (int k = 0; k < KD; ++k) Vm[k][t] = Vm[k][t] / n;
  }
  __syncthreads();
  if (t < KD) v0[t] = Vm[t][0];
  __syncthreads();

  // --- embed fixed columns: V_in = -cos(pi z) v0 + sin(pi z) perp_hat ---
  if (t < NTC) {
    float dt = 0.f;
#pragma unroll
    for (int k = 0; k < KD; ++k) dt += Vm[k][t] * v0[k];
    float pk[KD];
    float pn = 0.f;
#pragma unroll
    for (int k = 0; k < KD; ++k) {
      pk[k] = Vm[k][t] - v0[k] * dt;
      pn += pk[k] * pk[k];
    }
    pn = sqrtf(pn) + 1e-12f;
    if (fx[t]) {
      float ang = 3.14159265358979323846f * zfv[t];
      float c = -cosf(ang), sn = sinf(ang);
#pragma unroll
      for (int k = 0; k < KD; ++k) Vm[k][t] = fmaf(c, v0[k], sn * (pk[k] / pn));
    }
  }
  __syncthreads();

  // --- U = V * S  (18x16) ---
  for (int idx = t; idx < KD * MD; idx += 256) {
    int k = idx / MD, m = idx % MD;
    float s = 0.f;
    for (int c = 0; c < NTC; ++c) s += Vm[k][c] * Sm[c][m];
    Ul[k][m] = s;
  }
  __syncthreads();

  // --- mixing-method sweeps: single wave, lane = row k ---
  if (t < 64) {
    int k = t;
    bool act = (k < KD);
    float u[MD];
#pragma unroll
    for (int m = 0; m < MD; ++m) u[m] = act ? Ul[k][m] : 0.f;

    for (int sw = 0; sw < NSWEEP; ++sw) {
      for (int i = 1; i < NTC; ++i) {
        if (fx[i]) continue;  // fixed columns never change
        float4 s0 = *(const float4*)&Sm[i][0];
        float4 s1 = *(const float4*)&Sm[i][4];
        float4 s2 = *(const float4*)&Sm[i][8];
        float4 s3 = *(const float4*)&Sm[i][12];
        float vold = act ? Vm[k][i] : 0.f;
        // g = U s_i - Cd_i v_i  (== V C[:,i] - Cd_i v_i)
        float a0 = fmaf(u[0], s0.x, fmaf(u[1], s0.y, fmaf(u[2], s0.z, u[3] * s0.w)));
        float a1 = fmaf(u[4], s1.x, fmaf(u[5], s1.y, fmaf(u[6], s1.z, u[7] * s1.w)));
        float a2 = fmaf(u[8], s2.x, fmaf(u[9], s2.y, fmaf(u[10], s2.z, u[11] * s2.w)));
        float a3 = fmaf(u[12], s3.x, fmaf(u[13], s3.y, fmaf(u[14], s3.z, u[15] * s3.w)));
        float g = (a0 + a1) + (a2 + a3) - Cd[i] * vold;
        float g2 = g * g;
        g2 += __shfl_xor(g2, 16, 32);
        g2 += __shfl_xor(g2, 8, 32);
        g2 += __shfl_xor(g2, 4, 32);
        g2 += __shfl_xor(g2, 2, 32);
        g2 += __shfl_xor(g2, 1, 32);
        float inv = 1.0f / (sqrtf(g2) + 1e-12f);
        float vnew = -g * inv;
        float dd = vnew - vold;
#pragma unroll
        for (int m = 0; m < 4; ++m) {
          u[m] = fmaf(dd, ((const float*)&s0)[m], u[m]);
          u[4 + m] = fmaf(dd, ((const float*)&s1)[m], u[4 + m]);
          u[8 + m] = fmaf(dd, ((const float*)&s2)[m], u[8 + m]);
          u[12 + m] = fmaf(dd, ((const float*)&s3)[m], u[12 + m]);
        }
        if (act) Vm[k][i] = vnew;
      }
    }
  }
  __syncthreads();

  // --- outputs: zo for zf-columns 65..68 ---
  if (t < 4) {
    float dt = 0.f;
#pragma unroll
    for (int k = 0; k < KD; ++k) dt += Vm[k][65 + t] * v0[k];
    float x = -dt;
    x = fminf(fmaxf(x, -1.0f + 1e-6f), 1.0f - 1e-6f);
    out[t] = acosf(x) / 3.14159265358979323846f;
  }
}

extern "C" void kernel_launch(void* const* d_in, const int* in_sizes, int n_in,
                              void* d_out, int out_size, void* d_ws, size_t ws_size,
                              hipStream_t stream) {
  const float* points = (const float*)d_in[0];
  const float* features = (const float*)d_in[1];
  const float* W1 = (const float*)d_in[2];
  const float* b1 = (const float*)d_in[3];
  const float* S = (const float*)d_in[4];
  const int* is_input = (const int*)d_in[5];
  float* partials = (float*)d_ws;

  int nblk = NBLK_MAX;
  size_t need = (size_t)nblk * 64 * sizeof(float);
  if (ws_size < need) {
    nblk = (int)(ws_size / (64 * sizeof(float)));
    if (nblk < 1) nblk = 1;
  }

  hipLaunchKernelGGL(k1_reduce, dim3(nblk), dim3(256), 0, stream,
                     points, features, W1, b1, partials);
  hipLaunchKernelGGL(k2_satnet, dim3(1), dim3(256), 0, stream,
                     S, is_input, partials, nblk, (float*)d_out);
}

// Round 3
// 949.479 us; speedup vs baseline: 1.4446x; 1.4446x over previous
//
#include <hip/hip_runtime.h>
#include <math.h>

// Problem constants (from reference)
#define P_N    (1 << 20)   // points
#define NTC    133         // NT = N_VARS + AUX + 1
#define KD     18          // K = ceil(sqrt(2*NT))+1
#define MD     16          // M
#define NV     68          // N_VARS
#define NSWEEP 40
#define NBLK_MAX 512

__device__ __forceinline__ void threefry2x32(unsigned k0, unsigned k1,
                                             unsigned x0, unsigned x1,
                                             unsigned& o0, unsigned& o1) {
  unsigned ks2 = k0 ^ k1 ^ 0x1BD11BDAu;
#define TFR(r) { x0 += x1; x1 = (x1 << (r)) | (x1 >> (32 - (r))); x1 ^= x0; }
  x0 += k0; x1 += k1;
  TFR(13) TFR(15) TFR(26) TFR(6)
  x0 += k1;  x1 += ks2 + 1u;
  TFR(17) TFR(29) TFR(16) TFR(24)
  x0 += ks2; x1 += k0 + 2u;
  TFR(13) TFR(15) TFR(26) TFR(6)
  x0 += k0;  x1 += k1 + 3u;
  TFR(17) TFR(29) TFR(16) TFR(24)
  x0 += k1;  x1 += ks2 + 4u;
  TFR(13) TFR(15) TFR(26) TFR(6)
  x0 += ks2; x1 += k0 + 5u;
#undef TFR
  o0 = x0; o1 = x1;
}

// bits -> uniform exactly as jax._src.random._uniform, then sqrt(2)*erfinv.
__device__ __forceinline__ float bits_to_normal(unsigned b) {
  float f = __uint_as_float((b >> 9) | 0x3f800000u);  // [1,2)
  const float lo = -0.99999994f, hi = 1.0f;
  float d = hi - lo;
  float u = fmaf(f, d, lo - d);
  u = fmaxf(lo, u);
  float w = -logf((1.0f - u) * (1.0f + u));
  float p;
  if (w < 5.0f) {
    w -= 2.5f;
    p = 2.81022636e-08f;
    p = fmaf(p, w, 3.43273939e-07f);
    p = fmaf(p, w, -3.5233877e-06f);
    p = fmaf(p, w, -4.39150654e-06f);
    p = fmaf(p, w, 0.00021858087f);
    p = fmaf(p, w, -0.00125372503f);
    p = fmaf(p, w, -0.00417768164f);
    p = fmaf(p, w, 0.246640727f);
    p = fmaf(p, w, 1.50140941f);
  } else {
    w = sqrtf(w) - 3.0f;
    p = -0.000200214257f;
    p = fmaf(p, w, 0.000100950558f);
    p = fmaf(p, w, 0.00134934322f);
    p = fmaf(p, w, -0.00367342844f);
    p = fmaf(p, w, 0.00573950773f);
    p = fmaf(p, w, -0.0076224613f);
    p = fmaf(p, w, 0.00943887047f);
    p = fmaf(p, w, 1.00167406f);
    p = fmaf(p, w, 2.83297682f);
  }
  double y = (double)(p * u);
  const double Kc = 0.8862269254527580136490837416706;  // sqrt(pi)/2
  double ud = (double)u;
  y = y - (erf(y) - ud) * Kc * exp(y * y);
  y = y - (erf(y) - ud) * Kc * exp(y * y);
  return 1.41421356237309504880f * (float)y;
}

// DPP add-reduce step within a row of 16 lanes (CTRL is compile-time).
template <int CTRL>
__device__ __forceinline__ float dpp_add(float x) {
  int y = __builtin_amdgcn_update_dpp(0, __float_as_int(x), CTRL, 0xF, 0xF, true);
  return x + __int_as_float(y);
}

// ---------------- Kernel 1: streaming MLP reduction -------------------------
__global__ __launch_bounds__(256) void k1_reduce(
    const float* __restrict__ points, const float* __restrict__ features,
    const float* __restrict__ W1, const float* __restrict__ b1,
    float* __restrict__ partials) {
  __shared__ float red[4][64];
  float w0[16], w1[16], bb[16];
#pragma unroll
  for (int k = 0; k < 16; ++k) {
    w0[k] = W1[2 * k]; w1[k] = W1[2 * k + 1]; bb[k] = b1[k];
  }
  float acc[64];
#pragma unroll
  for (int e = 0; e < 64; ++e) acc[e] = 0.f;
  const float2* p2 = (const float2*)points;
  const float4* f4 = (const float4*)features;
  int gid = blockIdx.x * blockDim.x + threadIdx.x;
  int stride = gridDim.x * blockDim.x;
  for (int p = gid; p < P_N; p += stride) {
    float2 pt = p2[p];
    float4 ft = f4[p];
#pragma unroll
    for (int k = 0; k < 16; ++k) {
      float x = fmaf(pt.x, w0[k], fmaf(pt.y, w1[k], bb[k]));
      float h = 1.0f / (1.0f + __expf(-x));
      acc[4 * k + 0] = fmaf(h, ft.x, acc[4 * k + 0]);
      acc[4 * k + 1] = fmaf(h, ft.y, acc[4 * k + 1]);
      acc[4 * k + 2] = fmaf(h, ft.z, acc[4 * k + 2]);
      acc[4 * k + 3] = fmaf(h, ft.w, acc[4 * k + 3]);
    }
  }
#pragma unroll
  for (int e = 0; e < 64; ++e) {
    float v = acc[e];
    v += __shfl_down(v, 32);
    v += __shfl_down(v, 16);
    v += __shfl_down(v, 8);
    v += __shfl_down(v, 4);
    v += __shfl_down(v, 2);
    v += __shfl_down(v, 1);
    acc[e] = v;
  }
  int lane = threadIdx.x & 63, wv = threadIdx.x >> 6;
  if (lane == 0) {
#pragma unroll
    for (int e = 0; e < 64; ++e) red[wv][e] = acc[e];
  }
  __syncthreads();
  if (threadIdx.x < 64)
    partials[blockIdx.x * 64 + threadIdx.x] =
        red[0][threadIdx.x] + red[1][threadIdx.x] +
        red[2][threadIdx.x] + red[3][threadIdx.x];
}

// ---------------- Kernel 2: finalize + SATNet mixing ------------------------
__global__ __launch_bounds__(256) void k2_satnet(
    const float* __restrict__ S, const int* __restrict__ is_input,
    const float* __restrict__ partials, int nblk, float* __restrict__ out) {
  __shared__ float Vm[KD][NTC];
  __shared__ __align__(16) float Sm[NTC][MD];
  __shared__ float Cd[NTC];
  __shared__ float zfv[NTC];
  __shared__ int fx[NTC];
  __shared__ float v0[KD];
  __shared__ float Ul[KD][MD];
  __shared__ float red2[4][64];
  __shared__ int pattern_ok;

  int t = threadIdx.x;

  // --- reduce per-block partials ---
  {
    int g = t >> 6, e = t & 63;
    float s = 0.f;
    for (int b = g; b < nblk; b += 4) s += partials[b * 64 + e];
    red2[g][e] = s;
  }
  // --- load S ---
  for (int idx = t; idx < NTC * MD; idx += 256) ((float*)Sm)[idx] = S[idx];

  // --- V init: threefry normals (partitionable scheme) ---
  for (int e = t; e < KD * NTC; e += 256) {
    unsigned o0, o1;
    threefry2x32(0u, 42u, 0u, (unsigned)e, o0, o1);
    ((float*)Vm)[e] = bits_to_normal(o0 ^ o1);
  }
  __syncthreads();

  // --- zf, fixed mask, Cd ---
  if (t < NTC) {
    float zv = 0.f;
    if (t == 0) zv = 1.f;
    else if (t <= 64) {
      float x = red2[0][t - 1] + red2[1][t - 1] + red2[2][t - 1] + red2[3][t - 1];
      zv = 1.0f / (1.0f + expf(-x));
    }
    zfv[t] = zv;
    int f = 0;
    if (t == 0) f = 1;
    else if (t <= NV) f = (is_input[t - 1] != 0) ? 1 : 0;
    fx[t] = f;
    float cd = 0.f;
#pragma unroll
    for (int m = 0; m < MD; ++m) cd += Sm[t][m] * Sm[t][m];
    Cd[t] = cd;
  }
  __syncthreads();

  // --- verify assumed fixed/free pattern: fixed = 0..64, free = 65..132 ---
  if (t == 0) {
    int ok = 1;
    for (int i = 1; i <= 64; ++i) ok &= (fx[i] == 1);
    for (int i = 65; i < NTC; ++i) ok &= (fx[i] == 0);
    pattern_ok = ok;
  }

  // --- column-normalize V ---
  if (t < NTC) {
    float s = 0.f;
#pragma unroll
    for (int k = 0; k < KD; ++k) s += Vm[k][t] * Vm[k][t];
    float n = sqrtf(s);
#pragma unroll
    for (int k = 0; k < KD; ++k) Vm[k][t] = Vm[k][t] / n;
  }
  __syncthreads();
  if (t < KD) v0[t] = Vm[t][0];
  __syncthreads();

  // --- embed fixed columns ---
  if (t < NTC) {
    float dt = 0.f;
#pragma unroll
    for (int k = 0; k < KD; ++k) dt += Vm[k][t] * v0[k];
    float pk[KD];
    float pn = 0.f;
#pragma unroll
    for (int k = 0; k < KD; ++k) {
      pk[k] = Vm[k][t] - v0[k] * dt;
      pn += pk[k] * pk[k];
    }
    pn = sqrtf(pn) + 1e-12f;
    if (fx[t]) {
      float ang = 3.14159265358979323846f * zfv[t];
      float c = -cosf(ang), sn = sinf(ang);
#pragma unroll
      for (int k = 0; k < KD; ++k) Vm[k][t] = fmaf(c, v0[k], sn * (pk[k] / pn));
    }
  }
  __syncthreads();

  // --- U = V * S  (18x16) ---
  for (int idx = t; idx < KD * MD; idx += 256) {
    int k = idx / MD, m = idx % MD;
    float s = 0.f;
    for (int c = 0; c < NTC; ++c) s += Vm[k][c] * Sm[c][m];
    Ul[k][m] = s;
  }
  __syncthreads();

  if (pattern_ok) {
    // ---- fast path: lanes 0..31, lane = row k (rows >=18 compute zeros) ----
    if (t < 32) {
      const int k = t;
      const bool act = (k < KD);
      const int kc = act ? k : (KD - 1);
      float u[MD];
#pragma unroll
      for (int m = 0; m < MD; ++m) u[m] = act ? Ul[k][m] : 0.f;

      for (int sw = 0; sw < NSWEEP; ++sw) {
        // prefetch column 65
        float4 ps0 = *(const float4*)&Sm[65][0];
        float4 ps1 = *(const float4*)&Sm[65][4];
        float4 ps2 = *(const float4*)&Sm[65][8];
        float4 ps3 = *(const float4*)&Sm[65][12];
        float pcd = Cd[65];
        float ptv = Vm[kc][65];
        float pv = act ? ptv : 0.f;
#pragma unroll
        for (int i = 65; i < NTC; ++i) {
          float4 s0 = ps0, s1 = ps1, s2 = ps2, s3 = ps3;
          float cd = pcd, vold = pv;
          if (i < NTC - 1) {
            ps0 = *(const float4*)&Sm[i + 1][0];
            ps1 = *(const float4*)&Sm[i + 1][4];
            ps2 = *(const float4*)&Sm[i + 1][8];
            ps3 = *(const float4*)&Sm[i + 1][12];
            pcd = Cd[i + 1];
            float tv = Vm[kc][i + 1];
            pv = act ? tv : 0.f;
          }
          // g = U s_i - Cd_i v_i
          float a0 = fmaf(u[0], s0.x, fmaf(u[1], s0.y, fmaf(u[2], s0.z, u[3] * s0.w)));
          float a1 = fmaf(u[4], s1.x, fmaf(u[5], s1.y, fmaf(u[6], s1.z, u[7] * s1.w)));
          float a2 = fmaf(u[8], s2.x, fmaf(u[9], s2.y, fmaf(u[10], s2.z, u[11] * s2.w)));
          float a3 = fmaf(u[12], s3.x, fmaf(u[13], s3.y, fmaf(u[14], s3.z, u[15] * s3.w)));
          float g = (a0 + a1) + (a2 + a3) - cd * vold;
          float g2 = g * g;
          // 18-lane reduce: 4 DPP steps within row-of-16, one xor16 swizzle.
          g2 = dpp_add<0xB1>(g2);   // quad_perm xor1
          g2 = dpp_add<0x4E>(g2);   // quad_perm xor2
          g2 = dpp_add<0x124>(g2);  // row_ror:4
          g2 = dpp_add<0x128>(g2);  // row_ror:8
          {
            int y = __builtin_amdgcn_ds_swizzle(__float_as_int(g2), 0x401F);
            g2 += __int_as_float(y);
          }
          float inv;
          asm("v_rsq_f32 %0, %1" : "=v"(inv) : "v"(g2));
          float vnew = -g * inv;
          float dd = vnew - vold;
          u[0]  = fmaf(dd, s0.x, u[0]);
          u[1]  = fmaf(dd, s0.y, u[1]);
          u[2]  = fmaf(dd, s0.z, u[2]);
          u[3]  = fmaf(dd, s0.w, u[3]);
          u[4]  = fmaf(dd, s1.x, u[4]);
          u[5]  = fmaf(dd, s1.y, u[5]);
          u[6]  = fmaf(dd, s1.z, u[6]);
          u[7]  = fmaf(dd, s1.w, u[7]);
          u[8]  = fmaf(dd, s2.x, u[8]);
          u[9]  = fmaf(dd, s2.y, u[9]);
          u[10] = fmaf(dd, s2.z, u[10]);
          u[11] = fmaf(dd, s2.w, u[11]);
          u[12] = fmaf(dd, s3.x, u[12]);
          u[13] = fmaf(dd, s3.y, u[13]);
          u[14] = fmaf(dd, s3.z, u[14]);
          u[15] = fmaf(dd, s3.w, u[15]);
          if (act) Vm[k][i] = vnew;
        }
      }
    }
  } else {
    // ---- generic fallback: original single-wave shfl path ----
    if (t < 64) {
      int k = t;
      bool act = (k < KD);
      float u[MD];
#pragma unroll
      for (int m = 0; m < MD; ++m) u[m] = act ? Ul[k][m] : 0.f;
      for (int sw = 0; sw < NSWEEP; ++sw) {
        for (int i = 1; i < NTC; ++i) {
          if (fx[i]) continue;
          float4 s0 = *(const float4*)&Sm[i][0];
          float4 s1 = *(const float4*)&Sm[i][4];
          float4 s2 = *(const float4*)&Sm[i][8];
          float4 s3 = *(const float4*)&Sm[i][12];
          float vold = act ? Vm[k][i] : 0.f;
          float a0 = fmaf(u[0], s0.x, fmaf(u[1], s0.y, fmaf(u[2], s0.z, u[3] * s0.w)));
          float a1 = fmaf(u[4], s1.x, fmaf(u[5], s1.y, fmaf(u[6], s1.z, u[7] * s1.w)));
          float a2 = fmaf(u[8], s2.x, fmaf(u[9], s2.y, fmaf(u[10], s2.z, u[11] * s2.w)));
          float a3 = fmaf(u[12], s3.x, fmaf(u[13], s3.y, fmaf(u[14], s3.z, u[15] * s3.w)));
          float g = (a0 + a1) + (a2 + a3) - Cd[i] * vold;
          float g2 = g * g;
          g2 += __shfl_xor(g2, 16, 32);
          g2 += __shfl_xor(g2, 8, 32);
          g2 += __shfl_xor(g2, 4, 32);
          g2 += __shfl_xor(g2, 2, 32);
          g2 += __shfl_xor(g2, 1, 32);
          float inv = 1.0f / (sqrtf(g2) + 1e-12f);
          float vnew = -g * inv;
          float dd = vnew - vold;
#pragma unroll
          for (int m = 0; m < 4; ++m) {
            u[m] = fmaf(dd, ((const float*)&s0)[m], u[m]);
            u[4 + m] = fmaf(dd, ((const float*)&s1)[m], u[4 + m]);
            u[8 + m] = fmaf(dd, ((const float*)&s2)[m], u[8 + m]);
            u[12 + m] = fmaf(dd, ((const float*)&s3)[m], u[12 + m]);
          }
          if (act) Vm[k][i] = vnew;
        }
      }
    }
  }
  __syncthreads();

  // --- outputs: zo for zf-columns 65..68 ---
  if (t < 4) {
    float dt = 0.f;
#pragma unroll
    for (int k = 0; k < KD; ++k) dt += Vm[k][65 + t] * v0[k];
    float x = -dt;
    x = fminf(fmaxf(x, -1.0f + 1e-6f), 1.0f - 1e-6f);
    out[t] = acosf(x) / 3.14159265358979323846f;
  }
}

extern "C" void kernel_launch(void* const* d_in, const int* in_sizes, int n_in,
                              void* d_out, int out_size, void* d_ws, size_t ws_size,
                              hipStream_t stream) {
  const float* points = (const float*)d_in[0];
  const float* features = (const float*)d_in[1];
  const float* W1 = (const float*)d_in[2];
  const float* b1 = (const float*)d_in[3];
  const float* S = (const float*)d_in[4];
  const int* is_input = (const int*)d_in[5];
  float* partials = (float*)d_ws;

  int nblk = NBLK_MAX;
  size_t need = (size_t)nblk * 64 * sizeof(float);
  if (ws_size < need) {
    nblk = (int)(ws_size / (64 * sizeof(float)));
    if (nblk < 1) nblk = 1;
  }

  hipLaunchKernelGGL(k1_reduce, dim3(nblk), dim3(256), 0, stream,
                     points, features, W1, b1, partials);
  hipLaunchKernelGGL(k2_satnet, dim3(1), dim3(256), 0, stream,
                     S, is_input, partials, nblk, (float*)d_out);
}

// Round 5
// 621.285 us; speedup vs baseline: 2.2076x; 1.5282x over previous
//
#include <hip/hip_runtime.h>
#include <math.h>

// Problem constants (from reference)
#define P_N    (1 << 20)   // points
#define NTC    133         // NT = N_VARS + AUX + 1
#define KD     18          // K = ceil(sqrt(2*NT))+1
#define MD     16          // M
#define NV     68          // N_VARS
#define NSWEEP 40
#define NBLK_MAX 512

__device__ __forceinline__ void threefry2x32(unsigned k0, unsigned k1,
                                             unsigned x0, unsigned x1,
                                             unsigned& o0, unsigned& o1) {
  unsigned ks2 = k0 ^ k1 ^ 0x1BD11BDAu;
#define TFR(r) { x0 += x1; x1 = (x1 << (r)) | (x1 >> (32 - (r))); x1 ^= x0; }
  x0 += k0; x1 += k1;
  TFR(13) TFR(15) TFR(26) TFR(6)
  x0 += k1;  x1 += ks2 + 1u;
  TFR(17) TFR(29) TFR(16) TFR(24)
  x0 += ks2; x1 += k0 + 2u;
  TFR(13) TFR(15) TFR(26) TFR(6)
  x0 += k0;  x1 += k1 + 3u;
  TFR(17) TFR(29) TFR(16) TFR(24)
  x0 += k1;  x1 += ks2 + 4u;
  TFR(13) TFR(15) TFR(26) TFR(6)
  x0 += ks2; x1 += k0 + 5u;
#undef TFR
  o0 = x0; o1 = x1;
}

// bits -> uniform exactly as jax._src.random._uniform, then sqrt(2)*erfinv.
__device__ __forceinline__ float bits_to_normal(unsigned b) {
  float f = __uint_as_float((b >> 9) | 0x3f800000u);  // [1,2)
  const float lo = -0.99999994f, hi = 1.0f;
  float d = hi - lo;
  float u = fmaf(f, d, lo - d);
  u = fmaxf(lo, u);
  float w = -logf((1.0f - u) * (1.0f + u));
  float p;
  if (w < 5.0f) {
    w -= 2.5f;
    p = 2.81022636e-08f;
    p = fmaf(p, w, 3.43273939e-07f);
    p = fmaf(p, w, -3.5233877e-06f);
    p = fmaf(p, w, -4.39150654e-06f);
    p = fmaf(p, w, 0.00021858087f);
    p = fmaf(p, w, -0.00125372503f);
    p = fmaf(p, w, -0.00417768164f);
    p = fmaf(p, w, 0.246640727f);
    p = fmaf(p, w, 1.50140941f);
  } else {
    w = sqrtf(w) - 3.0f;
    p = -0.000200214257f;
    p = fmaf(p, w, 0.000100950558f);
    p = fmaf(p, w, 0.00134934322f);
    p = fmaf(p, w, -0.00367342844f);
    p = fmaf(p, w, 0.00573950773f);
    p = fmaf(p, w, -0.0076224613f);
    p = fmaf(p, w, 0.00943887047f);
    p = fmaf(p, w, 1.00167406f);
    p = fmaf(p, w, 2.83297682f);
  }
  double y = (double)(p * u);
  const double Kc = 0.8862269254527580136490837416706;  // sqrt(pi)/2
  double ud = (double)u;
  y = y - (erf(y) - ud) * Kc * exp(y * y);
  y = y - (erf(y) - ud) * Kc * exp(y * y);
  return 1.41421356237309504880f * (float)y;
}

// DPP add-reduce step within a row of 16 lanes (CTRL is compile-time).
template <int CTRL>
__device__ __forceinline__ float dpp_add(float x) {
  int y = __builtin_amdgcn_update_dpp(0, __float_as_int(x), CTRL, 0xF, 0xF, true);
  return x + __int_as_float(y);
}

// Merge the two 32-lane halves: returns (low-half value + high-half value)
// in every lane. Uses gfx950 v_permlane32_swap via builtin (T12 pattern).
__device__ __forceinline__ float cross_half_add(float g2) {
#if __has_builtin(__builtin_amdgcn_permlane32_swap)
  typedef unsigned uvec2 __attribute__((ext_vector_type(2)));
  uvec2 r = __builtin_amdgcn_permlane32_swap(__float_as_uint(g2),
                                             __float_as_uint(g2),
                                             false, false);
  // r[0]: lanes0..31 keep own, lanes32..63 get lane-32's value (low-half val)
  // r[1]: lanes0..31 get lane+32's value (high-half val), lanes32..63 keep own
  return __uint_as_float(r[0]) + __uint_as_float(r[1]);
#else
  return g2 + __shfl_xor(g2, 32, 64);
#endif
}

// ---------------- Kernel 1: streaming MLP reduction -------------------------
__global__ __launch_bounds__(256) void k1_reduce(
    const float* __restrict__ points, const float* __restrict__ features,
    const float* __restrict__ W1, const float* __restrict__ b1,
    float* __restrict__ partials) {
  __shared__ float red[4][64];
  float w0[16], w1[16], bb[16];
#pragma unroll
  for (int k = 0; k < 16; ++k) {
    w0[k] = W1[2 * k]; w1[k] = W1[2 * k + 1]; bb[k] = b1[k];
  }
  float acc[64];
#pragma unroll
  for (int e = 0; e < 64; ++e) acc[e] = 0.f;
  const float2* p2 = (const float2*)points;
  const float4* f4 = (const float4*)features;
  int gid = blockIdx.x * blockDim.x + threadIdx.x;
  int stride = gridDim.x * blockDim.x;
  for (int p = gid; p < P_N; p += stride) {
    float2 pt = p2[p];
    float4 ft = f4[p];
#pragma unroll
    for (int k = 0; k < 16; ++k) {
      float x = fmaf(pt.x, w0[k], fmaf(pt.y, w1[k], bb[k]));
      float h = 1.0f / (1.0f + __expf(-x));
      acc[4 * k + 0] = fmaf(h, ft.x, acc[4 * k + 0]);
      acc[4 * k + 1] = fmaf(h, ft.y, acc[4 * k + 1]);
      acc[4 * k + 2] = fmaf(h, ft.z, acc[4 * k + 2]);
      acc[4 * k + 3] = fmaf(h, ft.w, acc[4 * k + 3]);
    }
  }
#pragma unroll
  for (int e = 0; e < 64; ++e) {
    float v = acc[e];
    v += __shfl_down(v, 32);
    v += __shfl_down(v, 16);
    v += __shfl_down(v, 8);
    v += __shfl_down(v, 4);
    v += __shfl_down(v, 2);
    v += __shfl_down(v, 1);
    acc[e] = v;
  }
  int lane = threadIdx.x & 63, wv = threadIdx.x >> 6;
  if (lane == 0) {
#pragma unroll
    for (int e = 0; e < 64; ++e) red[wv][e] = acc[e];
  }
  __syncthreads();
  if (threadIdx.x < 64)
    partials[blockIdx.x * 64 + threadIdx.x] =
        red[0][threadIdx.x] + red[1][threadIdx.x] +
        red[2][threadIdx.x] + red[3][threadIdx.x];
}

// ---------------- Kernel 2: finalize + SATNet mixing ------------------------
__global__ __launch_bounds__(256) void k2_satnet(
    const float* __restrict__ S, const int* __restrict__ is_input,
    const float* __restrict__ partials, int nblk, float* __restrict__ out) {
  __shared__ float Vm[KD][NTC];
  __shared__ __align__(16) float Sm[NTC][MD];
  __shared__ float Cd[NTC];
  __shared__ float zfv[NTC];
  __shared__ int fx[NTC];
  __shared__ float v0[KD];
  __shared__ float Ul[KD][MD];
  __shared__ float red2[4][64];
  __shared__ int pattern_ok;

  int t = threadIdx.x;

  // --- reduce per-block partials ---
  {
    int g = t >> 6, e = t & 63;
    float s = 0.f;
    for (int b = g; b < nblk; b += 4) s += partials[b * 64 + e];
    red2[g][e] = s;
  }
  // --- load S ---
  for (int idx = t; idx < NTC * MD; idx += 256) ((float*)Sm)[idx] = S[idx];

  // --- V init: threefry normals (partitionable scheme) ---
  for (int e = t; e < KD * NTC; e += 256) {
    unsigned o0, o1;
    threefry2x32(0u, 42u, 0u, (unsigned)e, o0, o1);
    ((float*)Vm)[e] = bits_to_normal(o0 ^ o1);
  }
  __syncthreads();

  // --- zf, fixed mask, Cd ---
  if (t < NTC) {
    float zv = 0.f;
    if (t == 0) zv = 1.f;
    else if (t <= 64) {
      float x = red2[0][t - 1] + red2[1][t - 1] + red2[2][t - 1] + red2[3][t - 1];
      zv = 1.0f / (1.0f + expf(-x));
    }
    zfv[t] = zv;
    int f = 0;
    if (t == 0) f = 1;
    else if (t <= NV) f = (is_input[t - 1] != 0) ? 1 : 0;
    fx[t] = f;
    float cd = 0.f;
#pragma unroll
    for (int m = 0; m < MD; ++m) cd += Sm[t][m] * Sm[t][m];
    Cd[t] = cd;
  }
  __syncthreads();

  // --- verify assumed fixed/free pattern: fixed = 0..64, free = 65..132 ---
  if (t == 0) {
    int ok = 1;
    for (int i = 1; i <= 64; ++i) ok &= (fx[i] == 1);
    for (int i = 65; i < NTC; ++i) ok &= (fx[i] == 0);
    pattern_ok = ok;
  }

  // --- column-normalize V ---
  if (t < NTC) {
    float s = 0.f;
#pragma unroll
    for (int k = 0; k < KD; ++k) s += Vm[k][t] * Vm[k][t];
    float n = sqrtf(s);
#pragma unroll
    for (int k = 0; k < KD; ++k) Vm[k][t] = Vm[k][t] / n;
  }
  __syncthreads();
  if (t < KD) v0[t] = Vm[t][0];
  __syncthreads();

  // --- embed fixed columns ---
  if (t < NTC) {
    float dt = 0.f;
#pragma unroll
    for (int k = 0; k < KD; ++k) dt += Vm[k][t] * v0[k];
    float pk[KD];
    float pn = 0.f;
#pragma unroll
    for (int k = 0; k < KD; ++k) {
      pk[k] = Vm[k][t] - v0[k] * dt;
      pn += pk[k] * pk[k];
    }
    pn = sqrtf(pn) + 1e-12f;
    if (fx[t]) {
      float ang = 3.14159265358979323846f * zfv[t];
      float c = -cosf(ang), sn = sinf(ang);
#pragma unroll
      for (int k = 0; k < KD; ++k) Vm[k][t] = fmaf(c, v0[k], sn * (pk[k] / pn));
    }
  }
  __syncthreads();

  // --- U = V * S  (18x16) ---
  for (int idx = t; idx < KD * MD; idx += 256) {
    int k = idx / MD, m = idx % MD;
    float s = 0.f;
    for (int c = 0; c < NTC; ++c) s += Vm[k][c] * Sm[c][m];
    Ul[k][m] = s;
  }
  __syncthreads();

  if (pattern_ok) {
    // ---- fast path: wave 0. Rows 0..15 on lanes 0..15 (DPP row 0),
    //      rows 16..17 on lanes 32..33 (DPP row 2). Cross-half merge via
    //      v_permlane32_swap builtin (VALU, no LDS pipe). ----
    if (t < 64) {
      const int lane = t;
      const int row = (lane < 16) ? lane : (lane - 16);
      const bool act = (lane < 16) | (lane == 32) | (lane == 33);
      const int rc = act ? row : 0;
      float u[MD];
#pragma unroll
      for (int m = 0; m < MD; ++m) u[m] = act ? Ul[rc][m] : 0.f;

#pragma unroll 1
      for (int sw = 0; sw < NSWEEP; ++sw) {
        // prefetch column 65
        float4 ps0 = *(const float4*)&Sm[65][0];
        float4 ps1 = *(const float4*)&Sm[65][4];
        float4 ps2 = *(const float4*)&Sm[65][8];
        float4 ps3 = *(const float4*)&Sm[65][12];
        float pcd = Cd[65];
        float ptv = Vm[rc][65];
        float pv = act ? ptv : 0.f;
#pragma unroll 2
        for (int i = 65; i < NTC; ++i) {
          float4 s0 = ps0, s1 = ps1, s2 = ps2, s3 = ps3;
          float cd = pcd, vold = pv;
          if (i < NTC - 1) {
            ps0 = *(const float4*)&Sm[i + 1][0];
            ps1 = *(const float4*)&Sm[i + 1][4];
            ps2 = *(const float4*)&Sm[i + 1][8];
            ps3 = *(const float4*)&Sm[i + 1][12];
            pcd = Cd[i + 1];
            float tv = Vm[rc][i + 1];
            pv = act ? tv : 0.f;
          }
          // g = U s_i - Cd_i v_i
          float a0 = fmaf(u[0], s0.x, fmaf(u[1], s0.y, fmaf(u[2], s0.z, u[3] * s0.w)));
          float a1 = fmaf(u[4], s1.x, fmaf(u[5], s1.y, fmaf(u[6], s1.z, u[7] * s1.w)));
          float a2 = fmaf(u[8], s2.x, fmaf(u[9], s2.y, fmaf(u[10], s2.z, u[11] * s2.w)));
          float a3 = fmaf(u[12], s3.x, fmaf(u[13], s3.y, fmaf(u[14], s3.z, u[15] * s3.w)));
          float g = (a0 + a1) + (a2 + a3) - cd * vold;
          float g2 = g * g;
          // intra-row (16-lane) reduce: 4 DPP steps
          g2 = dpp_add<0xB1>(g2);   // quad_perm xor1
          g2 = dpp_add<0x4E>(g2);   // quad_perm xor2
          g2 = dpp_add<0x124>(g2);  // row_ror:4
          g2 = dpp_add<0x128>(g2);  // row_ror:8
          // merge low-half (rows 0..15) with high-half (rows 16,17)
          g2 = cross_half_add(g2);
          float inv;
          asm("v_rsq_f32 %0, %1" : "=v"(inv) : "v"(g2));
          float vnew = -g * inv;
          float dd = vnew - vold;
          u[0]  = fmaf(dd, s0.x, u[0]);
          u[1]  = fmaf(dd, s0.y, u[1]);
          u[2]  = fmaf(dd, s0.z, u[2]);
          u[3]  = fmaf(dd, s0.w, u[3]);
          u[4]  = fmaf(dd, s1.x, u[4]);
          u[5]  = fmaf(dd, s1.y, u[5]);
          u[6]  = fmaf(dd, s1.z, u[6]);
          u[7]  = fmaf(dd, s1.w, u[7]);
          u[8]  = fmaf(dd, s2.x, u[8]);
          u[9]  = fmaf(dd, s2.y, u[9]);
          u[10] = fmaf(dd, s2.z, u[10]);
          u[11] = fmaf(dd, s2.w, u[11]);
          u[12] = fmaf(dd, s3.x, u[12]);
          u[13] = fmaf(dd, s3.y, u[13]);
          u[14] = fmaf(dd, s3.z, u[14]);
          u[15] = fmaf(dd, s3.w, u[15]);
          if (act) Vm[rc][i] = vnew;
        }
      }
    }
  } else {
    // ---- generic fallback: original single-wave shfl path ----
    if (t < 64) {
      int k = t;
      bool act = (k < KD);
      float u[MD];
#pragma unroll
      for (int m = 0; m < MD; ++m) u[m] = act ? Ul[k][m] : 0.f;
#pragma unroll 1
      for (int sw = 0; sw < NSWEEP; ++sw) {
#pragma unroll 1
        for (int i = 1; i < NTC; ++i) {
          if (fx[i]) continue;
          float4 s0 = *(const float4*)&Sm[i][0];
          float4 s1 = *(const float4*)&Sm[i][4];
          float4 s2 = *(const float4*)&Sm[i][8];
          float4 s3 = *(const float4*)&Sm[i][12];
          float vold = act ? Vm[k][i] : 0.f;
          float a0 = fmaf(u[0], s0.x, fmaf(u[1], s0.y, fmaf(u[2], s0.z, u[3] * s0.w)));
          float a1 = fmaf(u[4], s1.x, fmaf(u[5], s1.y, fmaf(u[6], s1.z, u[7] * s1.w)));
          float a2 = fmaf(u[8], s2.x, fmaf(u[9], s2.y, fmaf(u[10], s2.z, u[11] * s2.w)));
          float a3 = fmaf(u[12], s3.x, fmaf(u[13], s3.y, fmaf(u[14], s3.z, u[15] * s3.w)));
          float g = (a0 + a1) + (a2 + a3) - Cd[i] * vold;
          float g2 = g * g;
          g2 += __shfl_xor(g2, 16, 32);
          g2 += __shfl_xor(g2, 8, 32);
          g2 += __shfl_xor(g2, 4, 32);
          g2 += __shfl_xor(g2, 2, 32);
          g2 += __shfl_xor(g2, 1, 32);
          float inv = 1.0f / (sqrtf(g2) + 1e-12f);
          float vnew = -g * inv;
          float dd = vnew - vold;
#pragma unroll
          for (int m = 0; m < 4; ++m) {
            u[m] = fmaf(dd, ((const float*)&s0)[m], u[m]);
            u[4 + m] = fmaf(dd, ((const float*)&s1)[m], u[4 + m]);
            u[8 + m] = fmaf(dd, ((const float*)&s2)[m], u[8 + m]);
            u[12 + m] = fmaf(dd, ((const float*)&s3)[m], u[12 + m]);
          }
          if (act) Vm[k][i] = vnew;
        }
      }
    }
  }
  __syncthreads();

  // --- outputs: zo for zf-columns 65..68 ---
  if (t < 4) {
    float dt = 0.f;
#pragma unroll
    for (int k = 0; k < KD; ++k) dt += Vm[k][65 + t] * v0[k];
    float x = -dt;
    x = fminf(fmaxf(x, -1.0f + 1e-6f), 1.0f - 1e-6f);
    out[t] = acosf(x) / 3.14159265358979323846f;
  }
}

extern "C" void kernel_launch(void* const* d_in, const int* in_sizes, int n_in,
                              void* d_out, int out_size, void* d_ws, size_t ws_size,
                              hipStream_t stream) {
  const float* points = (const float*)d_in[0];
  const float* features = (const float*)d_in[1];
  const float* W1 = (const float*)d_in[2];
  const float* b1 = (const float*)d_in[3];
  const float* S = (const float*)d_in[4];
  const int* is_input = (const int*)d_in[5];
  float* partials = (float*)d_ws;

  int nblk = NBLK_MAX;
  size_t need = (size_t)nblk * 64 * sizeof(float);
  if (ws_size < need) {
    nblk = (int)(ws_size / (64 * sizeof(float)));
    if (nblk < 1) nblk = 1;
  }

  hipLaunchKernelGGL(k1_reduce, dim3(nblk), dim3(256), 0, stream,
                     points, features, W1, b1, partials);
  hipLaunchKernelGGL(k2_satnet, dim3(1), dim3(256), 0, stream,
                     S, is_input, partials, nblk, (float*)d_out);
}

// Round 6
// 174.439 us; speedup vs baseline: 7.8628x; 3.5616x over previous
//
#include <hip/hip_runtime.h>
#include <math.h>

// Problem constants (from reference)
#define P_N    (1 << 20)   // points
#define NTC    133         // NT = N_VARS + AUX + 1
#define KD     18          // K = ceil(sqrt(2*NT))+1
#define MD     16          // M
#define NV     68          // N_VARS
#define NFREE  68          // free columns: 65..132
#define NSWEEP 40
#define NBLK_MAX 512

__device__ __forceinline__ void threefry2x32(unsigned k0, unsigned k1,
                                             unsigned x0, unsigned x1,
                                             unsigned& o0, unsigned& o1) {
  unsigned ks2 = k0 ^ k1 ^ 0x1BD11BDAu;
#define TFR(r) { x0 += x1; x1 = (x1 << (r)) | (x1 >> (32 - (r))); x1 ^= x0; }
  x0 += k0; x1 += k1;
  TFR(13) TFR(15) TFR(26) TFR(6)
  x0 += k1;  x1 += ks2 + 1u;
  TFR(17) TFR(29) TFR(16) TFR(24)
  x0 += ks2; x1 += k0 + 2u;
  TFR(13) TFR(15) TFR(26) TFR(6)
  x0 += k0;  x1 += k1 + 3u;
  TFR(17) TFR(29) TFR(16) TFR(24)
  x0 += k1;  x1 += ks2 + 4u;
  TFR(13) TFR(15) TFR(26) TFR(6)
  x0 += ks2; x1 += k0 + 5u;
#undef TFR
  o0 = x0; o1 = x1;
}

// bits -> uniform exactly as jax._src.random._uniform, then sqrt(2)*erfinv.
__device__ __forceinline__ float bits_to_normal(unsigned b) {
  float f = __uint_as_float((b >> 9) | 0x3f800000u);  // [1,2)
  const float lo = -0.99999994f, hi = 1.0f;
  float d = hi - lo;
  float u = fmaf(f, d, lo - d);
  u = fmaxf(lo, u);
  float w = -logf((1.0f - u) * (1.0f + u));
  float p;
  if (w < 5.0f) {
    w -= 2.5f;
    p = 2.81022636e-08f;
    p = fmaf(p, w, 3.43273939e-07f);
    p = fmaf(p, w, -3.5233877e-06f);
    p = fmaf(p, w, -4.39150654e-06f);
    p = fmaf(p, w, 0.00021858087f);
    p = fmaf(p, w, -0.00125372503f);
    p = fmaf(p, w, -0.00417768164f);
    p = fmaf(p, w, 0.246640727f);
    p = fmaf(p, w, 1.50140941f);
  } else {
    w = sqrtf(w) - 3.0f;
    p = -0.000200214257f;
    p = fmaf(p, w, 0.000100950558f);
    p = fmaf(p, w, 0.00134934322f);
    p = fmaf(p, w, -0.00367342844f);
    p = fmaf(p, w, 0.00573950773f);
    p = fmaf(p, w, -0.0076224613f);
    p = fmaf(p, w, 0.00943887047f);
    p = fmaf(p, w, 1.00167406f);
    p = fmaf(p, w, 2.83297682f);
  }
  double y = (double)(p * u);
  const double Kc = 0.8862269254527580136490837416706;  // sqrt(pi)/2
  double ud = (double)u;
  y = y - (erf(y) - ud) * Kc * exp(y * y);
  y = y - (erf(y) - ud) * Kc * exp(y * y);
  return 1.41421356237309504880f * (float)y;
}

// DPP add-reduce step within a row of 16 lanes (CTRL is compile-time).
template <int CTRL>
__device__ __forceinline__ float dpp_add(float x) {
  int y = __builtin_amdgcn_update_dpp(0, __float_as_int(x), CTRL, 0xF, 0xF, true);
  return x + __int_as_float(y);
}

// Merge the two 32-lane halves: returns (low-half value + high-half value)
// in every lane. Uses gfx950 v_permlane32_swap via builtin (T12 pattern).
__device__ __forceinline__ float cross_half_add(float g2) {
#if __has_builtin(__builtin_amdgcn_permlane32_swap)
  typedef unsigned uvec2 __attribute__((ext_vector_type(2)));
  uvec2 r = __builtin_amdgcn_permlane32_swap(__float_as_uint(g2),
                                             __float_as_uint(g2),
                                             false, false);
  return __uint_as_float(r[0]) + __uint_as_float(r[1]);
#else
  return g2 + __shfl_xor(g2, 32, 64);
#endif
}

// ---------------- Kernel 1: streaming MLP reduction -------------------------
__global__ __launch_bounds__(256) void k1_reduce(
    const float* __restrict__ points, const float* __restrict__ features,
    const float* __restrict__ W1, const float* __restrict__ b1,
    float* __restrict__ partials) {
  __shared__ float red[4][64];
  float w0[16], w1[16], bb[16];
#pragma unroll
  for (int k = 0; k < 16; ++k) {
    w0[k] = W1[2 * k]; w1[k] = W1[2 * k + 1]; bb[k] = b1[k];
  }
  float acc[64];
#pragma unroll
  for (int e = 0; e < 64; ++e) acc[e] = 0.f;
  const float2* p2 = (const float2*)points;
  const float4* f4 = (const float4*)features;
  int gid = blockIdx.x * blockDim.x + threadIdx.x;
  int stride = gridDim.x * blockDim.x;
  for (int p = gid; p < P_N; p += stride) {
    float2 pt = p2[p];
    float4 ft = f4[p];
#pragma unroll
    for (int k = 0; k < 16; ++k) {
      float x = fmaf(pt.x, w0[k], fmaf(pt.y, w1[k], bb[k]));
      float h = 1.0f / (1.0f + __expf(-x));
      acc[4 * k + 0] = fmaf(h, ft.x, acc[4 * k + 0]);
      acc[4 * k + 1] = fmaf(h, ft.y, acc[4 * k + 1]);
      acc[4 * k + 2] = fmaf(h, ft.z, acc[4 * k + 2]);
      acc[4 * k + 3] = fmaf(h, ft.w, acc[4 * k + 3]);
    }
  }
#pragma unroll
  for (int e = 0; e < 64; ++e) {
    float v = acc[e];
    v += __shfl_down(v, 32);
    v += __shfl_down(v, 16);
    v += __shfl_down(v, 8);
    v += __shfl_down(v, 4);
    v += __shfl_down(v, 2);
    v += __shfl_down(v, 1);
    acc[e] = v;
  }
  int lane = threadIdx.x & 63, wv = threadIdx.x >> 6;
  if (lane == 0) {
#pragma unroll
    for (int e = 0; e < 64; ++e) red[wv][e] = acc[e];
  }
  __syncthreads();
  if (threadIdx.x < 64)
    partials[blockIdx.x * 64 + threadIdx.x] =
        red[0][threadIdx.x] + red[1][threadIdx.x] +
        red[2][threadIdx.x] + red[3][threadIdx.x];
}

// ---------------- Kernel 2: finalize + SATNet mixing ------------------------
__global__ __launch_bounds__(256) void k2_satnet(
    const float* __restrict__ S, const int* __restrict__ is_input,
    const float* __restrict__ partials, int nblk, float* __restrict__ out) {
  __shared__ float Vm[KD][NTC];
  __shared__ __align__(16) float Sm[NTC][MD];
  __shared__ float Cd[NTC];
  __shared__ float zfv[NTC];
  __shared__ int fx[NTC];
  __shared__ float v0[KD];
  __shared__ float Ul[KD][MD];
  __shared__ float red2[4][64];
  __shared__ int pattern_ok;

  int t = threadIdx.x;

  // --- reduce per-block partials ---
  {
    int g = t >> 6, e = t & 63;
    float s = 0.f;
    for (int b = g; b < nblk; b += 4) s += partials[b * 64 + e];
    red2[g][e] = s;
  }
  // --- load S ---
  for (int idx = t; idx < NTC * MD; idx += 256) ((float*)Sm)[idx] = S[idx];

  // --- V init: threefry normals (partitionable scheme) ---
  for (int e = t; e < KD * NTC; e += 256) {
    unsigned o0, o1;
    threefry2x32(0u, 42u, 0u, (unsigned)e, o0, o1);
    ((float*)Vm)[e] = bits_to_normal(o0 ^ o1);
  }
  __syncthreads();

  // --- zf, fixed mask, Cd ---
  if (t < NTC) {
    float zv = 0.f;
    if (t == 0) zv = 1.f;
    else if (t <= 64) {
      float x = red2[0][t - 1] + red2[1][t - 1] + red2[2][t - 1] + red2[3][t - 1];
      zv = 1.0f / (1.0f + expf(-x));
    }
    zfv[t] = zv;
    int f = 0;
    if (t == 0) f = 1;
    else if (t <= NV) f = (is_input[t - 1] != 0) ? 1 : 0;
    fx[t] = f;
    float cd = 0.f;
#pragma unroll
    for (int m = 0; m < MD; ++m) cd += Sm[t][m] * Sm[t][m];
    Cd[t] = cd;
  }
  __syncthreads();

  // --- verify assumed fixed/free pattern: fixed = 0..64, free = 65..132 ---
  if (t == 0) {
    int ok = 1;
    for (int i = 1; i <= 64; ++i) ok &= (fx[i] == 1);
    for (int i = 65; i < NTC; ++i) ok &= (fx[i] == 0);
    pattern_ok = ok;
  }

  // --- column-normalize V ---
  if (t < NTC) {
    float s = 0.f;
#pragma unroll
    for (int k = 0; k < KD; ++k) s += Vm[k][t] * Vm[k][t];
    float n = sqrtf(s);
#pragma unroll
    for (int k = 0; k < KD; ++k) Vm[k][t] = Vm[k][t] / n;
  }
  __syncthreads();
  if (t < KD) v0[t] = Vm[t][0];
  __syncthreads();

  // --- embed fixed columns ---
  if (t < NTC) {
    float dt = 0.f;
#pragma unroll
    for (int k = 0; k < KD; ++k) dt += Vm[k][t] * v0[k];
    float pk[KD];
    float pn = 0.f;
#pragma unroll
    for (int k = 0; k < KD; ++k) {
      pk[k] = Vm[k][t] - v0[k] * dt;
      pn += pk[k] * pk[k];
    }
    pn = sqrtf(pn) + 1e-12f;
    if (fx[t]) {
      float ang = 3.14159265358979323846f * zfv[t];
      float c = -cosf(ang), sn = sinf(ang);
#pragma unroll
      for (int k = 0; k < KD; ++k) Vm[k][t] = fmaf(c, v0[k], sn * (pk[k] / pn));
    }
  }
  __syncthreads();

  // --- U = V * S  (18x16) ---
  for (int idx = t; idx < KD * MD; idx += 256) {
    int k = idx / MD, m = idx % MD;
    float s = 0.f;
    for (int c = 0; c < NTC; ++c) s += Vm[k][c] * Sm[c][m];
    Ul[k][m] = s;
  }
  __syncthreads();

  if (pattern_ok) {
    // ---- fast path: wave 0. Rows 0..15 on lanes 0..15 (DPP row 0),
    //      rows 16..17 on lanes 32..33 (DPP row 2). V free columns held in
    //      registers (static indexing via full unroll); only S/Cd prefetch
    //      loads touch LDS in the loop. sched_barrier(0) seals each column
    //      region so the compiler can't hoist loads across iterations
    //      (round-3 spill cause). Early-exit when a sweep is a no-op. ----
    if (t < 64) {
      const int lane = t;
      const int row = (lane < 16) ? lane : (lane - 16);
      const bool act = (lane < 16) | (lane == 32) | (lane == 33);
      const int rc = act ? row : 0;
      float u[MD];
#pragma unroll
      for (int m = 0; m < MD; ++m) u[m] = act ? Ul[rc][m] : 0.f;
      float vr[NFREE];
#pragma unroll
      for (int j = 0; j < NFREE; ++j) vr[j] = act ? Vm[rc][65 + j] : 0.f;

#pragma unroll 1
      for (int sw = 0; sw < NSWEEP; ++sw) {
        float maxdd = 0.f;
        // prologue: prefetch column 65 (j=0)
        float4 ps0 = *(const float4*)&Sm[65][0];
        float4 ps1 = *(const float4*)&Sm[65][4];
        float4 ps2 = *(const float4*)&Sm[65][8];
        float4 ps3 = *(const float4*)&Sm[65][12];
        float pcd = Cd[65];
#pragma unroll
        for (int j = 0; j < NFREE; ++j) {
          float4 s0 = ps0, s1 = ps1, s2 = ps2, s3 = ps3;
          float cd = pcd;
          if (j < NFREE - 1) {
            ps0 = *(const float4*)&Sm[66 + j][0];
            ps1 = *(const float4*)&Sm[66 + j][4];
            ps2 = *(const float4*)&Sm[66 + j][8];
            ps3 = *(const float4*)&Sm[66 + j][12];
            pcd = Cd[66 + j];
          }
          float vold = vr[j];
          // g = U s_i - Cd_i v_i
          float a0 = fmaf(u[0], s0.x, fmaf(u[1], s0.y, fmaf(u[2], s0.z, u[3] * s0.w)));
          float a1 = fmaf(u[4], s1.x, fmaf(u[5], s1.y, fmaf(u[6], s1.z, u[7] * s1.w)));
          float a2 = fmaf(u[8], s2.x, fmaf(u[9], s2.y, fmaf(u[10], s2.z, u[11] * s2.w)));
          float a3 = fmaf(u[12], s3.x, fmaf(u[13], s3.y, fmaf(u[14], s3.z, u[15] * s3.w)));
          float g = (a0 + a1) + (a2 + a3) - cd * vold;
          float g2 = g * g;
          // intra-row (16-lane) reduce: 4 DPP steps
          g2 = dpp_add<0xB1>(g2);   // quad_perm xor1
          g2 = dpp_add<0x4E>(g2);   // quad_perm xor2
          g2 = dpp_add<0x124>(g2);  // row_ror:4
          g2 = dpp_add<0x128>(g2);  // row_ror:8
          // merge low-half (rows 0..15) with high-half (rows 16,17)
          g2 = cross_half_add(g2);
          float inv;
          asm("v_rsq_f32 %0, %1" : "=v"(inv) : "v"(g2));
          float vnew = -g * inv;   // inactive lanes: g==0 -> vnew==0
          float dd = vnew - vold;
          vr[j] = vnew;
          u[0]  = fmaf(dd, s0.x, u[0]);
          u[1]  = fmaf(dd, s0.y, u[1]);
          u[2]  = fmaf(dd, s0.z, u[2]);
          u[3]  = fmaf(dd, s0.w, u[3]);
          u[4]  = fmaf(dd, s1.x, u[4]);
          u[5]  = fmaf(dd, s1.y, u[5]);
          u[6]  = fmaf(dd, s1.z, u[6]);
          u[7]  = fmaf(dd, s1.w, u[7]);
          u[8]  = fmaf(dd, s2.x, u[8]);
          u[9]  = fmaf(dd, s2.y, u[9]);
          u[10] = fmaf(dd, s2.z, u[10]);
          u[11] = fmaf(dd, s2.w, u[11]);
          u[12] = fmaf(dd, s3.x, u[12]);
          u[13] = fmaf(dd, s3.y, u[13]);
          u[14] = fmaf(dd, s3.z, u[14]);
          u[15] = fmaf(dd, s3.w, u[15]);
          maxdd = fmaxf(maxdd, fabsf(dd));
          __builtin_amdgcn_sched_barrier(0);
        }
        // converged sweep: subsequent sweeps are numerically inert
        if (__all(maxdd < 1e-6f)) break;
      }
      // write back only the output columns (65..68)
      if (act) {
#pragma unroll
        for (int j = 0; j < 4; ++j) Vm[rc][65 + j] = vr[j];
      }
    }
  } else {
    // ---- generic fallback: original single-wave shfl path ----
    if (t < 64) {
      int k = t;
      bool act = (k < KD);
      float u[MD];
#pragma unroll
      for (int m = 0; m < MD; ++m) u[m] = act ? Ul[k][m] : 0.f;
#pragma unroll 1
      for (int sw = 0; sw < NSWEEP; ++sw) {
#pragma unroll 1
        for (int i = 1; i < NTC; ++i) {
          if (fx[i]) continue;
          float4 s0 = *(const float4*)&Sm[i][0];
          float4 s1 = *(const float4*)&Sm[i][4];
          float4 s2 = *(const float4*)&Sm[i][8];
          float4 s3 = *(const float4*)&Sm[i][12];
          float vold = act ? Vm[k][i] : 0.f;
          float a0 = fmaf(u[0], s0.x, fmaf(u[1], s0.y, fmaf(u[2], s0.z, u[3] * s0.w)));
          float a1 = fmaf(u[4], s1.x, fmaf(u[5], s1.y, fmaf(u[6], s1.z, u[7] * s1.w)));
          float a2 = fmaf(u[8], s2.x, fmaf(u[9], s2.y, fmaf(u[10], s2.z, u[11] * s2.w)));
          float a3 = fmaf(u[12], s3.x, fmaf(u[13], s3.y, fmaf(u[14], s3.z, u[15] * s3.w)));
          float g = (a0 + a1) + (a2 + a3) - Cd[i] * vold;
          float g2 = g * g;
          g2 += __shfl_xor(g2, 16, 32);
          g2 += __shfl_xor(g2, 8, 32);
          g2 += __shfl_xor(g2, 4, 32);
          g2 += __shfl_xor(g2, 2, 32);
          g2 += __shfl_xor(g2, 1, 32);
          float inv = 1.0f / (sqrtf(g2) + 1e-12f);
          float vnew = -g * inv;
          float dd = vnew - vold;
#pragma unroll
          for (int m = 0; m < 4; ++m) {
            u[m] = fmaf(dd, ((const float*)&s0)[m], u[m]);
            u[4 + m] = fmaf(dd, ((const float*)&s1)[m], u[4 + m]);
            u[8 + m] = fmaf(dd, ((const float*)&s2)[m], u[8 + m]);
            u[12 + m] = fmaf(dd, ((const float*)&s3)[m], u[12 + m]);
          }
          if (act) Vm[k][i] = vnew;
        }
      }
    }
  }
  __syncthreads();

  // --- outputs: zo for zf-columns 65..68 ---
  if (t < 4) {
    float dt = 0.f;
#pragma unroll
    for (int k = 0; k < KD; ++k) dt += Vm[k][65 + t] * v0[k];
    float x = -dt;
    x = fminf(fmaxf(x, -1.0f + 1e-6f), 1.0f - 1e-6f);
    out[t] = acosf(x) / 3.14159265358979323846f;
  }
}

extern "C" void kernel_launch(void* const* d_in, const int* in_sizes, int n_in,
                              void* d_out, int out_size, void* d_ws, size_t ws_size,
                              hipStream_t stream) {
  const float* points = (const float*)d_in[0];
  const float* features = (const float*)d_in[1];
  const float* W1 = (const float*)d_in[2];
  const float* b1 = (const float*)d_in[3];
  const float* S = (const float*)d_in[4];
  const int* is_input = (const int*)d_in[5];
  float* partials = (float*)d_ws;

  int nblk = NBLK_MAX;
  size_t need = (size_t)nblk * 64 * sizeof(float);
  if (ws_size < need) {
    nblk = (int)(ws_size / (64 * sizeof(float)));
    if (nblk < 1) nblk = 1;
  }

  hipLaunchKernelGGL(k1_reduce, dim3(nblk), dim3(256), 0, stream,
                     points, features, W1, b1, partials);
  hipLaunchKernelGGL(k2_satnet, dim3(1), dim3(256), 0, stream,
                     S, is_input, partials, nblk, (float*)d_out);
}

// Round 7
// 144.287 us; speedup vs baseline: 9.5059x; 1.2090x over previous
//
#include <hip/hip_runtime.h>
#include <math.h>

// Problem constants (from reference)
#define P_N    (1 << 20)   // points
#define NTC    133         // NT = N_VARS + AUX + 1
#define KD     18          // K = ceil(sqrt(2*NT))+1
#define MD     16          // M
#define NV     68          // N_VARS
#define NFREE  68          // free columns: 65..132
#define NSWEEP 40
#define NBLK_MAX 512

typedef float float2v __attribute__((ext_vector_type(2)));

__device__ __forceinline__ void threefry2x32(unsigned k0, unsigned k1,
                                             unsigned x0, unsigned x1,
                                             unsigned& o0, unsigned& o1) {
  unsigned ks2 = k0 ^ k1 ^ 0x1BD11BDAu;
#define TFR(r) { x0 += x1; x1 = (x1 << (r)) | (x1 >> (32 - (r))); x1 ^= x0; }
  x0 += k0; x1 += k1;
  TFR(13) TFR(15) TFR(26) TFR(6)
  x0 += k1;  x1 += ks2 + 1u;
  TFR(17) TFR(29) TFR(16) TFR(24)
  x0 += ks2; x1 += k0 + 2u;
  TFR(13) TFR(15) TFR(26) TFR(6)
  x0 += k0;  x1 += k1 + 3u;
  TFR(17) TFR(29) TFR(16) TFR(24)
  x0 += k1;  x1 += ks2 + 4u;
  TFR(13) TFR(15) TFR(26) TFR(6)
  x0 += ks2; x1 += k0 + 5u;
#undef TFR
  o0 = x0; o1 = x1;
}

// bits -> uniform exactly as jax._src.random._uniform, then sqrt(2)*erfinv.
// Giles f32 poly + ONE double Newton step (quadratic: ~1e-13 rel, f32-exact).
__device__ __forceinline__ float bits_to_normal(unsigned b) {
  float f = __uint_as_float((b >> 9) | 0x3f800000u);  // [1,2)
  const float lo = -0.99999994f, hi = 1.0f;
  float d = hi - lo;
  float u = fmaf(f, d, lo - d);
  u = fmaxf(lo, u);
  float w = -logf((1.0f - u) * (1.0f + u));
  float p;
  if (w < 5.0f) {
    w -= 2.5f;
    p = 2.81022636e-08f;
    p = fmaf(p, w, 3.43273939e-07f);
    p = fmaf(p, w, -3.5233877e-06f);
    p = fmaf(p, w, -4.39150654e-06f);
    p = fmaf(p, w, 0.00021858087f);
    p = fmaf(p, w, -0.00125372503f);
    p = fmaf(p, w, -0.00417768164f);
    p = fmaf(p, w, 0.246640727f);
    p = fmaf(p, w, 1.50140941f);
  } else {
    w = sqrtf(w) - 3.0f;
    p = -0.000200214257f;
    p = fmaf(p, w, 0.000100950558f);
    p = fmaf(p, w, 0.00134934322f);
    p = fmaf(p, w, -0.00367342844f);
    p = fmaf(p, w, 0.00573950773f);
    p = fmaf(p, w, -0.0076224613f);
    p = fmaf(p, w, 0.00943887047f);
    p = fmaf(p, w, 1.00167406f);
    p = fmaf(p, w, 2.83297682f);
  }
  double y = (double)(p * u);
  const double Kc = 0.8862269254527580136490837416706;  // sqrt(pi)/2
  double ud = (double)u;
  y = y - (erf(y) - ud) * Kc * exp(y * y);
  return 1.41421356237309504880f * (float)y;
}

// DPP add-reduce step within a row of 16 lanes (CTRL is compile-time).
template <int CTRL>
__device__ __forceinline__ float dpp_add(float x) {
  int y = __builtin_amdgcn_update_dpp(0, __float_as_int(x), CTRL, 0xF, 0xF, true);
  return x + __int_as_float(y);
}

// Merge the two 32-lane halves: returns (low-half value + high-half value)
// in every lane. Uses gfx950 v_permlane32_swap via builtin (T12 pattern).
__device__ __forceinline__ float cross_half_add(float g2) {
#if __has_builtin(__builtin_amdgcn_permlane32_swap)
  typedef unsigned uvec2 __attribute__((ext_vector_type(2)));
  uvec2 r = __builtin_amdgcn_permlane32_swap(__float_as_uint(g2),
                                             __float_as_uint(g2),
                                             false, false);
  return __uint_as_float(r[0]) + __uint_as_float(r[1]);
#else
  return g2 + __shfl_xor(g2, 32, 64);
#endif
}

// Packed f32 math (VOP3P, gfx90a+).
__device__ __forceinline__ float2v pk_fma(float2v a, float2v b, float2v c) {
  float2v d;
  asm("v_pk_fma_f32 %0, %1, %2, %3" : "=v"(d) : "v"(a), "v"(b), "v"(c));
  return d;
}
__device__ __forceinline__ float2v pk_mul(float2v a, float2v b) {
  float2v d;
  asm("v_pk_mul_f32 %0, %1, %2" : "=v"(d) : "v"(a), "v"(b));
  return d;
}

// packed 16-dot: a[0..7] . b[0..7] (each float2v)
__device__ __forceinline__ float dot16p(const float2v* a, const float2v* b) {
  float2v acc0 = pk_mul(a[0], b[0]);
  float2v acc1 = pk_mul(a[1], b[1]);
  acc0 = pk_fma(a[2], b[2], acc0);
  acc1 = pk_fma(a[3], b[3], acc1);
  acc0 = pk_fma(a[4], b[4], acc0);
  acc1 = pk_fma(a[5], b[5], acc1);
  acc0 = pk_fma(a[6], b[6], acc0);
  acc1 = pk_fma(a[7], b[7], acc1);
  return (acc0.x + acc1.x) + (acc0.y + acc1.y);
}

// ---------------- Kernel 1: streaming MLP reduction -------------------------
__global__ __launch_bounds__(256) void k1_reduce(
    const float* __restrict__ points, const float* __restrict__ features,
    const float* __restrict__ W1, const float* __restrict__ b1,
    float* __restrict__ partials) {
  __shared__ float red[4][64];
  float w0[16], w1[16], bb[16];
#pragma unroll
  for (int k = 0; k < 16; ++k) {
    w0[k] = W1[2 * k]; w1[k] = W1[2 * k + 1]; bb[k] = b1[k];
  }
  float acc[64];
#pragma unroll
  for (int e = 0; e < 64; ++e) acc[e] = 0.f;
  const float2* p2 = (const float2*)points;
  const float4* f4 = (const float4*)features;
  int gid = blockIdx.x * blockDim.x + threadIdx.x;
  int stride = gridDim.x * blockDim.x;
  for (int p = gid; p < P_N; p += stride) {
    float2 pt = p2[p];
    float4 ft = f4[p];
#pragma unroll
    for (int k = 0; k < 16; ++k) {
      float x = fmaf(pt.x, w0[k], fmaf(pt.y, w1[k], bb[k]));
      float h = 1.0f / (1.0f + __expf(-x));
      acc[4 * k + 0] = fmaf(h, ft.x, acc[4 * k + 0]);
      acc[4 * k + 1] = fmaf(h, ft.y, acc[4 * k + 1]);
      acc[4 * k + 2] = fmaf(h, ft.z, acc[4 * k + 2]);
      acc[4 * k + 3] = fmaf(h, ft.w, acc[4 * k + 3]);
    }
  }
#pragma unroll
  for (int e = 0; e < 64; ++e) {
    float v = acc[e];
    v += __shfl_down(v, 32);
    v += __shfl_down(v, 16);
    v += __shfl_down(v, 8);
    v += __shfl_down(v, 4);
    v += __shfl_down(v, 2);
    v += __shfl_down(v, 1);
    acc[e] = v;
  }
  int lane = threadIdx.x & 63, wv = threadIdx.x >> 6;
  if (lane == 0) {
#pragma unroll
    for (int e = 0; e < 64; ++e) red[wv][e] = acc[e];
  }
  __syncthreads();
  if (threadIdx.x < 64)
    partials[blockIdx.x * 64 + threadIdx.x] =
        red[0][threadIdx.x] + red[1][threadIdx.x] +
        red[2][threadIdx.x] + red[3][threadIdx.x];
}

// ---------------- Kernel 2: finalize + SATNet mixing ------------------------
__global__ __launch_bounds__(256) void k2_satnet(
    const float* __restrict__ S, const int* __restrict__ is_input,
    const float* __restrict__ partials, int nblk, float* __restrict__ out) {
  __shared__ float Vm[KD][NTC];
  __shared__ __align__(16) float Sm[NTC][MD];
  __shared__ float Cd[NTC];
  __shared__ float Cp[NFREE];   // Cp[j] = S_col(65+j) . S_col(65+(j+1)%68)
  __shared__ float zfv[NTC];
  __shared__ int fx[NTC];
  __shared__ float v0[KD];
  __shared__ float Ul[KD][MD];
  __shared__ float red2[4][64];
  __shared__ int pattern_ok;

  int t = threadIdx.x;

  // --- reduce per-block partials ---
  {
    int g = t >> 6, e = t & 63;
    float s = 0.f;
    for (int b = g; b < nblk; b += 4) s += partials[b * 64 + e];
    red2[g][e] = s;
  }
  // --- load S ---
  for (int idx = t; idx < NTC * MD; idx += 256) ((float*)Sm)[idx] = S[idx];

  // --- V init: threefry normals (partitionable scheme) ---
  for (int e = t; e < KD * NTC; e += 256) {
    unsigned o0, o1;
    threefry2x32(0u, 42u, 0u, (unsigned)e, o0, o1);
    ((float*)Vm)[e] = bits_to_normal(o0 ^ o1);
  }
  __syncthreads();

  // --- zf, fixed mask, Cd ---
  if (t < NTC) {
    float zv = 0.f;
    if (t == 0) zv = 1.f;
    else if (t <= 64) {
      float x = red2[0][t - 1] + red2[1][t - 1] + red2[2][t - 1] + red2[3][t - 1];
      zv = 1.0f / (1.0f + expf(-x));
    }
    zfv[t] = zv;
    int f = 0;
    if (t == 0) f = 1;
    else if (t <= NV) f = (is_input[t - 1] != 0) ? 1 : 0;
    fx[t] = f;
    float cd = 0.f;
#pragma unroll
    for (int m = 0; m < MD; ++m) cd += Sm[t][m] * Sm[t][m];
    Cd[t] = cd;
  }
  // --- adjacent-pair dots for the lookahead correction ---
  if (t < NFREE) {
    int a = 65 + t, b = 65 + ((t + 1) % NFREE);
    float s = 0.f;
#pragma unroll
    for (int m = 0; m < MD; ++m) s += Sm[a][m] * Sm[b][m];
    Cp[t] = s;
  }
  __syncthreads();

  // --- verify assumed fixed/free pattern: fixed = 0..64, free = 65..132 ---
  if (t == 0) {
    int ok = 1;
    for (int i = 1; i <= 64; ++i) ok &= (fx[i] == 1);
    for (int i = 65; i < NTC; ++i) ok &= (fx[i] == 0);
    pattern_ok = ok;
  }

  // --- column-normalize V ---
  if (t < NTC) {
    float s = 0.f;
#pragma unroll
    for (int k = 0; k < KD; ++k) s += Vm[k][t] * Vm[k][t];
    float n = sqrtf(s);
#pragma unroll
    for (int k = 0; k < KD; ++k) Vm[k][t] = Vm[k][t] / n;
  }
  __syncthreads();
  if (t < KD) v0[t] = Vm[t][0];
  __syncthreads();

  // --- embed fixed columns ---
  if (t < NTC) {
    float dt = 0.f;
#pragma unroll
    for (int k = 0; k < KD; ++k) dt += Vm[k][t] * v0[k];
    float pk[KD];
    float pn = 0.f;
#pragma unroll
    for (int k = 0; k < KD; ++k) {
      pk[k] = Vm[k][t] - v0[k] * dt;
      pn += pk[k] * pk[k];
    }
    pn = sqrtf(pn) + 1e-12f;
    if (fx[t]) {
      float ang = 3.14159265358979323846f * zfv[t];
      float c = -cosf(ang), sn = sinf(ang);
#pragma unroll
      for (int k = 0; k < KD; ++k) Vm[k][t] = fmaf(c, v0[k], sn * (pk[k] / pn));
    }
  }
  __syncthreads();

  // --- U = V * S  (18x16) ---
  for (int idx = t; idx < KD * MD; idx += 256) {
    int k = idx / MD, m = idx % MD;
    float s = 0.f;
    for (int c = 0; c < NTC; ++c) s += Vm[k][c] * Sm[c][m];
    Ul[k][m] = s;
  }
  __syncthreads();

  if (pattern_ok) {
    // ---- fast path: wave 0. Rows 0..15 on lanes 0..15 (DPP row 0),
    //      rows 16..17 on lanes 32..33 (DPP row 2).
    //      Lookahead: g_j = pre_j + dd_{j-1}*Cp[j-1] - cd_j*v_j, with
    //      pre_j = U(state j-2) . s_j computed during column j-1's reduce —
    //      the 16-FMA dot leaves the critical chain.
    //      Ring-4 prefetch (68%4==0 -> slot map sweep-invariant): loads
    //      issued 3 regions ahead of use. Packed v_pk_fma_f32 halves the
    //      dot/update instruction count. ----
    if (t < 64) {
      const int lane = t;
      const int row = (lane < 16) ? lane : (lane - 16);
      const bool act = (lane < 16) | (lane == 32) | (lane == 33);
      const int rc = act ? row : 0;

      float2v u2[8];
#pragma unroll
      for (int m = 0; m < 8; ++m) {
        float2v z; z.x = act ? Ul[rc][2 * m] : 0.f; z.y = act ? Ul[rc][2 * m + 1] : 0.f;
        u2[m] = z;
      }
      float vr[NFREE];
#pragma unroll
      for (int j = 0; j < NFREE; ++j) vr[j] = act ? Vm[rc][65 + j] : 0.f;

      // ring-4 state
      float2v rs2[4][8];
      float rcd[4], rcp[4];
#pragma unroll
      for (int s = 0; s < 3; ++s) {
        float4 q0 = *(const float4*)&Sm[65 + s][0];
        float4 q1 = *(const float4*)&Sm[65 + s][4];
        float4 q2 = *(const float4*)&Sm[65 + s][8];
        float4 q3 = *(const float4*)&Sm[65 + s][12];
        rs2[s][0].x = q0.x; rs2[s][0].y = q0.y;
        rs2[s][1].x = q0.z; rs2[s][1].y = q0.w;
        rs2[s][2].x = q1.x; rs2[s][2].y = q1.y;
        rs2[s][3].x = q1.z; rs2[s][3].y = q1.w;
        rs2[s][4].x = q2.x; rs2[s][4].y = q2.y;
        rs2[s][5].x = q2.z; rs2[s][5].y = q2.w;
        rs2[s][6].x = q3.x; rs2[s][6].y = q3.y;
        rs2[s][7].x = q3.z; rs2[s][7].y = q3.w;
        rcd[s] = Cd[65 + s];
        rcp[s] = Cp[s];
      }
      rcp[3] = Cp[NFREE - 1];  // cp[67] for the j=0 carry (x0 on sweep 0)
      rcd[3] = 0.f;

      float pre = dot16p(u2, rs2[0]);
      float ddp = 0.f;

#pragma unroll 1
      for (int sw = 0; sw < NSWEEP; ++sw) {
        float maxdd = 0.f;
#pragma unroll
        for (int j = 0; j < NFREE; ++j) {
          const int c = j & 3, n = (j + 1) & 3, w = (j + 3) & 3;
          const int colw = (j + 3) % NFREE;
          // carries / ring reads (before ring writes)
          float cp_prev = rcp[w];   // Cp[j-1]
          float cdj = rcd[c];
          float vold = vr[j];
          // issue loads for column j+3
          float4 t0 = *(const float4*)&Sm[65 + colw][0];
          float4 t1 = *(const float4*)&Sm[65 + colw][4];
          float4 t2 = *(const float4*)&Sm[65 + colw][8];
          float4 t3 = *(const float4*)&Sm[65 + colw][12];
          float tcd = Cd[65 + colw];
          float tcp = Cp[colw];
          // ---- critical chain ----
          float g = fmaf(ddp, cp_prev, pre);
          g = fmaf(-cdj, vold, g);
          float g2 = g * g;
          g2 = dpp_add<0xB1>(g2);   // quad_perm xor1
          g2 = dpp_add<0x4E>(g2);   // quad_perm xor2
          g2 = dpp_add<0x124>(g2);  // row_ror:4
          g2 = dpp_add<0x128>(g2);  // row_ror:8
          g2 = cross_half_add(g2);
          float inv;
          asm("v_rsq_f32 %0, %1" : "=v"(inv) : "v"(g2));
          float vnew = -g * inv;
          float dd = vnew - vold;
          // ---- off-path: lookahead dot with pre-update U ----
          float pre_next = dot16p(u2, rs2[n]);
          // ---- u update ----
          float2v dd2; dd2.x = dd; dd2.y = dd;
#pragma unroll
          for (int m = 0; m < 8; ++m) u2[m] = pk_fma(dd2, rs2[c][m], u2[m]);
          vr[j] = vnew;
          maxdd = fmaxf(maxdd, fabsf(dd));
          pre = pre_next;
          ddp = dd;
          // fill ring
          rs2[w][0].x = t0.x; rs2[w][0].y = t0.y;
          rs2[w][1].x = t0.z; rs2[w][1].y = t0.w;
          rs2[w][2].x = t1.x; rs2[w][2].y = t1.y;
          rs2[w][3].x = t1.z; rs2[w][3].y = t1.w;
          rs2[w][4].x = t2.x; rs2[w][4].y = t2.y;
          rs2[w][5].x = t2.z; rs2[w][5].y = t2.w;
          rs2[w][6].x = t3.x; rs2[w][6].y = t3.y;
          rs2[w][7].x = t3.z; rs2[w][7].y = t3.w;
          rcd[w] = tcd;
          rcp[w] = tcp;
          __builtin_amdgcn_sched_barrier(0);
        }
        // converged sweep: subsequent sweeps are numerically inert
        if (__all(maxdd < 1e-6f)) break;
      }
      // write back only the output columns (65..68)
      if (act) {
#pragma unroll
        for (int j = 0; j < 4; ++j) Vm[rc][65 + j] = vr[j];
      }
    }
  } else {
    // ---- generic fallback: original single-wave shfl path ----
    if (t < 64) {
      int k = t;
      bool act = (k < KD);
      float u[MD];
#pragma unroll
      for (int m = 0; m < MD; ++m) u[m] = act ? Ul[k][m] : 0.f;
#pragma unroll 1
      for (int sw = 0; sw < NSWEEP; ++sw) {
#pragma unroll 1
        for (int i = 1; i < NTC; ++i) {
          if (fx[i]) continue;
          float4 s0 = *(const float4*)&Sm[i][0];
          float4 s1 = *(const float4*)&Sm[i][4];
          float4 s2 = *(const float4*)&Sm[i][8];
          float4 s3 = *(const float4*)&Sm[i][12];
          float vold = act ? Vm[k][i] : 0.f;
          float a0 = fmaf(u[0], s0.x, fmaf(u[1], s0.y, fmaf(u[2], s0.z, u[3] * s0.w)));
          float a1 = fmaf(u[4], s1.x, fmaf(u[5], s1.y, fmaf(u[6], s1.z, u[7] * s1.w)));
          float a2 = fmaf(u[8], s2.x, fmaf(u[9], s2.y, fmaf(u[10], s2.z, u[11] * s2.w)));
          float a3 = fmaf(u[12], s3.x, fmaf(u[13], s3.y, fmaf(u[14], s3.z, u[15] * s3.w)));
          float g = (a0 + a1) + (a2 + a3) - Cd[i] * vold;
          float g2 = g * g;
          g2 += __shfl_xor(g2, 16, 32);
          g2 += __shfl_xor(g2, 8, 32);
          g2 += __shfl_xor(g2, 4, 32);
          g2 += __shfl_xor(g2, 2, 32);
          g2 += __shfl_xor(g2, 1, 32);
          float inv = 1.0f / (sqrtf(g2) + 1e-12f);
          float vnew = -g * inv;
          float dd = vnew - vold;
#pragma unroll
          for (int m = 0; m < 4; ++m) {
            u[m] = fmaf(dd, ((const float*)&s0)[m], u[m]);
            u[4 + m] = fmaf(dd, ((const float*)&s1)[m], u[4 + m]);
            u[8 + m] = fmaf(dd, ((const float*)&s2)[m], u[8 + m]);
            u[12 + m] = fmaf(dd, ((const float*)&s3)[m], u[12 + m]);
          }
          if (act) Vm[k][i] = vnew;
        }
      }
    }
  }
  __syncthreads();

  // --- outputs: zo for zf-columns 65..68 ---
  if (t < 4) {
    float dt = 0.f;
#pragma unroll
    for (int k = 0; k < KD; ++k) dt += Vm[k][65 + t] * v0[k];
    float x = -dt;
    x = fminf(fmaxf(x, -1.0f + 1e-6f), 1.0f - 1e-6f);
    out[t] = acosf(x) / 3.14159265358979323846f;
  }
}

extern "C" void kernel_launch(void* const* d_in, const int* in_sizes, int n_in,
                              void* d_out, int out_size, void* d_ws, size_t ws_size,
                              hipStream_t stream) {
  const float* points = (const float*)d_in[0];
  const float* features = (const float*)d_in[1];
  const float* W1 = (const float*)d_in[2];
  const float* b1 = (const float*)d_in[3];
  const float* S = (const float*)d_in[4];
  const int* is_input = (const int*)d_in[5];
  float* partials = (float*)d_ws;

  int nblk = NBLK_MAX;
  size_t need = (size_t)nblk * 64 * sizeof(float);
  if (ws_size < need) {
    nblk = (int)(ws_size / (64 * sizeof(float)));
    if (nblk < 1) nblk = 1;
  }

  hipLaunchKernelGGL(k1_reduce, dim3(nblk), dim3(256), 0, stream,
                     points, features, W1, b1, partials);
  hipLaunchKernelGGL(k2_satnet, dim3(1), dim3(256), 0, stream,
                     S, is_input, partials, nblk, (float*)d_out);
}